// Round 7
// baseline (1169.828 us; speedup 1.0000x reference)
//
#include <hip/hip_runtime.h>
#include <hip/hip_bf16.h>

// CharDecoder: T=21, B=4096, H=1024, E=50, V=96
// d_out: scores(T,B,V) fp32 | h_T(B,H) | c_T(B,H)

#define T_STEPS 21
#define BSZ 4096
#define HDIM 1024
#define VOCAB 96
#define EDIM 50

typedef __attribute__((ext_vector_type(8))) short short8;
typedef __attribute__((ext_vector_type(4))) short shortx4;
typedef __attribute__((ext_vector_type(4))) float f32x4;

#define GLL16(g, l)                                                        \
  __builtin_amdgcn_global_load_lds(                                        \
      (const __attribute__((address_space(1))) void*)(g),                  \
      (__attribute__((address_space(3))) void*)(l), 16, 0, 0)

#define ASM_BARRIER() asm volatile("s_barrier" ::: "memory")
#define ASM_VMCNT3() asm volatile("s_waitcnt vmcnt(3)" ::: "memory")
#define ASM_VMCNT0() asm volatile("s_waitcnt vmcnt(0)" ::: "memory")

__device__ __forceinline__ float sigmoidf_fast(float x) {
  return 1.0f / (1.0f + __expf(-x));
}
__device__ __forceinline__ float tanhf_fast(float x) {
  return 2.0f / (1.0f + __expf(-2.0f * x)) - 1.0f;
}
__device__ __forceinline__ float b2f(short s) {
  return __uint_as_float(((unsigned int)(unsigned short)s) << 16);
}

// ---- prep: fp32 -> bf16 weight/state conversion -------------------------
__global__ void prep_convert(const float* __restrict__ Whh_f,
                             const float* __restrict__ Wout_f,
                             const float* __restrict__ h0,
                             __hip_bfloat16* __restrict__ Whh,
                             __hip_bfloat16* __restrict__ Wout,
                             __hip_bfloat16* __restrict__ hb0) {
  int idx = blockIdx.x * 256 + threadIdx.x;
  if (idx < 4 * HDIM * HDIM) {
    Whh[idx] = __float2bfloat16(Whh_f[idx]);
    hb0[idx] = __float2bfloat16(h0[idx]);
  }
  if (idx < VOCAB * HDIM) Wout[idx] = __float2bfloat16(Wout_f[idx]);
}

// ---- prep: Pb[j>>5][v][unit 32][gate 4] (bf16) = emb.W_ih + b_ih + b_hh -
__global__ void prep_ptable(const float* __restrict__ emb,
                            const float* __restrict__ Wih,
                            const float* __restrict__ bih,
                            const float* __restrict__ bhh,
                            __hip_bfloat16* __restrict__ Pb) {
  int idx = blockIdx.x * 256 + threadIdx.x;  // 96*4096
  int v = idx >> 12, g = idx & 4095;         // g = gate*1024 + j
  int gate = g >> 10, j = g & 1023;
  const float* er = emb + v * EDIM;
  const float* wr = Wih + g * EDIM;
  float s = bih[g] + bhh[g];
#pragma unroll 10
  for (int e = 0; e < EDIM; ++e) s += er[e] * wr[e];
  Pb[(size_t)(j >> 5) * 12288 + v * 128 + (j & 31) * 4 + gate] =
      __float2bfloat16(s);
}

// ---- 256x128 LSTM step, BK=32, triple-buffered, 2 blocks/CU -------------
// Tile: 256 batch rows x (4 gates x 32 units); grid 512; 8 waves (4M x 2N);
// LDS 3 bufs x 24KB (A 128 lines x 128B + B 64 lines x 128B) = 72KB ->
// 2 blocks/CU (144KB LDS, 16 waves/CU) -- the occupancy fix for R6's
// barrier-lockstep exposure (R4->R6 proved reads/barriers weren't binding).
// LDS byte layout packs row pairs: line = row>>1, slot S in [0,8) of 16B,
// S = ((row&1)<<2)|kslot, stored at slot' = S ^ (line&7) (R6's swizzle).
// Per tile k (single phase): 8 ds_read_b128 || stage tile k+2 (3 GLL16) ->
// barrier -> 16 MFMA (setprio) -> vmcnt(3) -> barrier.
// Regions: stage at k targets buf((k+2)%3)=buf(k-1), free since
// barrier2(k-1). vmcnt proof: at tile k, outstanding = tile k+1's 3
// (issued at k-1) + tile k+2's 3 (just issued); vmcnt(3) drains k+1's ->
// ~1.5 tiles latency cover. k==30: vmcnt(0) (no stage); k==31: none.

#define TILE(kk, CB, SB, DOSTAGE, VMW)                                      \
  {                                                                         \
    const __hip_bfloat16* bufE =                                            \
        (const __hip_bfloat16*)(smem + (CB) * 24576);                       \
    short8 af[4], bf[4];                                                    \
    _Pragma("unroll") for (int mi = 0; mi < 4; ++mi)                        \
        af[mi] = *(const short8*)&bufE[a_off[mi]];                          \
    _Pragma("unroll") for (int g = 0; g < 4; ++g)                           \
        bf[g] = *(const short8*)&bufE[b_off[g]];                            \
    if (DOSTAGE) {                                                          \
      GLL16(hprev + aSrc[0] + ((kk) + 2) * 32,                              \
            smem + (SB) * 24576 + aDstB0);                                  \
      GLL16(hprev + aSrc[1] + ((kk) + 2) * 32,                              \
            smem + (SB) * 24576 + aDstB1);                                  \
      GLL16(Whh + bSrcE + ((kk) + 2) * 32, smem + (SB) * 24576 + bDstB);    \
    }                                                                       \
    ASM_BARRIER();                                                          \
    __builtin_amdgcn_s_setprio(1);                                          \
    _Pragma("unroll") for (int mi = 0; mi < 4; ++mi)                        \
        _Pragma("unroll") for (int g = 0; g < 4; ++g)                       \
            acc[mi][g] = __builtin_amdgcn_mfma_f32_16x16x32_bf16(           \
                af[mi], bf[g], acc[mi][g], 0, 0, 0);                        \
    __builtin_amdgcn_s_setprio(0);                                          \
    VMW;                                                                    \
    ASM_BARRIER();                                                          \
  }

template <bool LAST>
__global__ __launch_bounds__(512, 4) void lstm_step_kernel(
    const int* __restrict__ ids,               // B ints (this t)
    const __hip_bfloat16* __restrict__ hprev,  // B x H
    const __hip_bfloat16* __restrict__ Whh,    // 4H x H (torch order i,f,g,o)
    const __hip_bfloat16* __restrict__ Pb,     // 32 x 96 x 32 x 4 (bf16)
    const float* __restrict__ c_in,            // B x H
    float* __restrict__ c_out,                 // B x H
    __hip_bfloat16* __restrict__ hnext,        // B x H
    float* __restrict__ hf32)                  // B x H (LAST only)
{
  __shared__ __align__(16) char smem[73728];  // 3 x 24KB

  const int tid = threadIdx.x;
  const int wid = tid >> 6;
  const int lane = tid & 63;
  const int wr = wid >> 1;  // 0..3 (M quarter: 64 rows)
  const int wc = wid & 1;   // 0..1 (N half: 16 units x 4 gates)
  const int u16 = lane & 15;
  const int k16q = lane >> 4;

  // XCD swizzle: blocks sharing mt (bid = x mod 16) land on one XCD.
  const int bid = blockIdx.x;
  const int mt = (bid & 7) * 2 + ((bid >> 3) & 1);  // 0..15
  const int jt = bid >> 4;                          // 0..31 (32-unit block)
  const int m0 = mt * 256;

  // ---- fragment read offsets (elements), swizzled row-pair layout ----
  // A: lines [0,128) at elem 0; B: lines [0,64) at elem 8192.
  int a_off[4], b_off[4];
  {
    const int S = ((u16 & 1) << 2) | k16q;
#pragma unroll
    for (int mi = 0; mi < 4; ++mi) {
      const int La = wr * 32 + mi * 8 + (u16 >> 1);
      a_off[mi] = La * 64 + (S ^ (La & 7)) * 8;
    }
#pragma unroll
    for (int g = 0; g < 4; ++g) {
      const int Lb = wc * 32 + g * 8 + (u16 >> 1);
      b_off[g] = 8192 + Lb * 64 + (S ^ (Lb & 7)) * 8;
    }
  }

  // ---- staging bases (pre-swizzled global sources, linear LDS dest) ----
  size_t aSrc[2];
  size_t bSrcE;
  const int aDstB0 = wid * 2048;
  const int aDstB1 = wid * 2048 + 1024;
  const int bDstB = 16384 + wid * 1024;
  {
    const int Sp = lane & 7;  // slot' written by this lane
#pragma unroll
    for (int i = 0; i < 2; ++i) {
      const int La = wid * 16 + i * 8 + (lane >> 3);
      const int S = Sp ^ (La & 7);
      const int mrow = 2 * La + (S >> 2);
      aSrc[i] = (size_t)(m0 + mrow) * HDIM + (S & 3) * 8;
    }
    const int Lb = wid * 8 + (lane >> 3);
    const int S = Sp ^ (Lb & 7);
    const int n = 2 * Lb + (S >> 2);
    const int wcg = n >> 6, gate = (n >> 4) & 3, u = n & 15;
    bSrcE = (size_t)(gate * HDIM + jt * 32 + wcg * 16 + u) * HDIM +
            (S & 3) * 8;
  }

  // prologue: tile 0 -> buf0, tile 1 -> buf1
  GLL16(hprev + aSrc[0], smem + aDstB0);
  GLL16(hprev + aSrc[1], smem + aDstB1);
  GLL16(Whh + bSrcE, smem + bDstB);
  GLL16(hprev + aSrc[0] + 32, smem + 24576 + aDstB0);
  GLL16(hprev + aSrc[1] + 32, smem + 24576 + aDstB1);
  GLL16(Whh + bSrcE + 32, smem + 24576 + bDstB);
  ASM_VMCNT3();  // tile 0 landed; tile 1's 3 in flight
  ASM_BARRIER();

  f32x4 acc[4][4] = {};  // [m-frag][gate]

#pragma unroll 1
  for (int kb = 0; kb < 30; kb += 3) {
    TILE(kb, 0, 2, true, ASM_VMCNT3());
    TILE(kb + 1, 1, 0, true, ASM_VMCNT3());
    TILE(kb + 2, 2, 1, true, ASM_VMCNT3());
  }
  TILE(30, 0, 2, false, ASM_VMCNT0());
  TILE(31, 1, 0, false, {});

  // c_in prefetch (overlaps Pb staging below); disjoint (row,jcol) tiles.
  const int jcol = jt * 32 + wc * 16 + u16;  // output unit j
  float cpre[4][4];
#pragma unroll
  for (int mi = 0; mi < 4; ++mi)
#pragma unroll
    for (int r = 0; r < 4; ++r)
      cpre[mi][r] = c_in[(size_t)(m0 + wr * 64 + mi * 16 + k16q * 4 + r) *
                             HDIM +
                         jcol];

  // stage bf16 P slice (24 KB) into buf0 (free since tile 30's barrier).
  {
    const __hip_bfloat16* Pbj = Pb + (size_t)jt * 12288;
#pragma unroll
    for (int i = 0; i < 3; ++i)
      GLL16(Pbj + (wid * 3 + i) * 512 + lane * 8,
            smem + (wid * 3 + i) * 1024);
  }
  ASM_VMCNT0();
  ASM_BARRIER();

  // epilogue: 16 outputs/lane; 4 gates of unit jcol contiguous (b64 read)
  const __hip_bfloat16* sPb = (const __hip_bfloat16*)smem;
  const int uo4 = (wc * 16 + u16) * 4;
  const int rb = m0 + wr * 64 + k16q * 4;
#pragma unroll
  for (int mi = 0; mi < 4; ++mi) {
#pragma unroll
    for (int r = 0; r < 4; ++r) {
      const int row = rb + mi * 16 + r;
      const int id = ids[row];
      const shortx4 pv = *(const shortx4*)&sPb[id * 128 + uo4];
      float iv = acc[mi][0][r] + b2f(pv[0]);
      float fv = acc[mi][1][r] + b2f(pv[1]);
      float gv = acc[mi][2][r] + b2f(pv[2]);
      float ov = acc[mi][3][r] + b2f(pv[3]);
      iv = sigmoidf_fast(iv);
      fv = sigmoidf_fast(fv);
      gv = tanhf_fast(gv);
      ov = sigmoidf_fast(ov);
      const size_t off = (size_t)row * HDIM + jcol;
      const float cc = fv * cpre[mi][r] + iv * gv;
      c_out[off] = cc;
      const float hh = ov * tanhf_fast(cc);
      hnext[off] = __float2bfloat16(hh);
      if (LAST) hf32[off] = hh;
    }
  }
}

// ---- scores: LDS-tiled GEMM, 128 rows x 96 cols per block, BK=128 -------
__global__ __launch_bounds__(256, 2) void scores_kernel(
    const __hip_bfloat16* __restrict__ h,     // rows x H (bf16)
    const __hip_bfloat16* __restrict__ Wout,  // 96 x H
    const float* __restrict__ bout,           // 96
    float* __restrict__ out)                  // rows x 96
{
  __shared__ __align__(16) __hip_bfloat16 sA[128 * 128];  // 32 KB
  __shared__ __align__(16) __hip_bfloat16 sB[96 * 128];   // 24 KB

  const int tid = threadIdx.x;
  const int wave = tid >> 6, lane = tid & 63;
  const int u16 = lane & 15, k16q = lane >> 4;
  const long r0 = (long)blockIdx.x * 128;

  f32x4 acc[2][6] = {};  // wave: 32 rows x 96 cols

  const int srow4 = lane >> 4;
  const int sslot = lane & 15;

  for (int k0 = 0; k0 < HDIM; k0 += 128) {
#pragma unroll
    for (int i = 0; i < 8; ++i) {  // A: 32 rows/wave
      int row = wave * 32 + i * 4 + srow4;
      int gg = sslot ^ (row & 15);
      GLL16(h + (r0 + row) * HDIM + k0 + gg * 8,
            &sA[(wave * 32 + i * 4) * 128]);
    }
#pragma unroll
    for (int i = 0; i < 6; ++i) {  // B: 24 rows/wave
      int row = wave * 24 + i * 4 + srow4;
      int gg = sslot ^ (row & 15);
      GLL16(Wout + (size_t)row * HDIM + k0 + gg * 8,
            &sB[(wave * 24 + i * 4) * 128]);
    }
    __syncthreads();
#pragma unroll
    for (int kk = 0; kk < 128; kk += 32) {
      const int sl = (((kk >> 3) + k16q) ^ u16) * 8;
      short8 af[2], bf[6];
#pragma unroll
      for (int mi = 0; mi < 2; ++mi)
        af[mi] = *(const short8*)&sA[(wave * 32 + mi * 16 + u16) * 128 + sl];
#pragma unroll
      for (int ni = 0; ni < 6; ++ni)
        bf[ni] = *(const short8*)&sB[(ni * 16 + u16) * 128 + sl];
#pragma unroll
      for (int mi = 0; mi < 2; ++mi)
#pragma unroll
        for (int ni = 0; ni < 6; ++ni)
          acc[mi][ni] = __builtin_amdgcn_mfma_f32_16x16x32_bf16(
              af[mi], bf[ni], acc[mi][ni], 0, 0, 0);
    }
    __syncthreads();
  }

#pragma unroll
  for (int ni = 0; ni < 6; ++ni) {
    int v = ni * 16 + u16;
    float bv = bout[v];
#pragma unroll
    for (int mi = 0; mi < 2; ++mi)
#pragma unroll
      for (int r = 0; r < 4; ++r) {
        long grow = r0 + wave * 32 + mi * 16 + k16q * 4 + r;
        out[grow * VOCAB + v] = acc[mi][ni][r] + bv;
      }
  }
}

extern "C" void kernel_launch(void* const* d_in, const int* in_sizes, int n_in,
                              void* d_out, int out_size, void* d_ws,
                              size_t ws_size, hipStream_t stream) {
  const int* ids = (const int*)d_in[0];
  const float* h0 = (const float*)d_in[1];
  const float* c0 = (const float*)d_in[2];
  const float* emb = (const float*)d_in[3];
  const float* Wih = (const float*)d_in[4];
  const float* Whh_f = (const float*)d_in[5];
  const float* bih = (const float*)d_in[6];
  const float* bhh = (const float*)d_in[7];
  const float* Wout_f = (const float*)d_in[8];
  const float* bout = (const float*)d_in[9];

  float* out = (float*)d_out;
  float* scores = out;                              // T*B*V
  float* hT = out + (size_t)T_STEPS * BSZ * VOCAB;  // B*H
  float* cT = hT + (size_t)BSZ * HDIM;              // B*H

  const size_t BH = (size_t)BSZ * HDIM;
  char* w = (char*)d_ws;
  __hip_bfloat16* Pb = (__hip_bfloat16*)w;   w += (size_t)32 * 12288 * 2;
  __hip_bfloat16* Whh = (__hip_bfloat16*)w;  w += (size_t)4 * HDIM * HDIM * 2;
  __hip_bfloat16* Wout = (__hip_bfloat16*)w; w += (size_t)VOCAB * HDIM * 2;
  __hip_bfloat16* hts = (__hip_bfloat16*)w;  // 22*BH (full) or 2*BH (pingpong)
  size_t base = (size_t)32 * 12288 * 2 + (size_t)4 * HDIM * HDIM * 2 +
                (size_t)VOCAB * HDIM * 2;
  const bool full = ws_size >= base + (size_t)(T_STEPS + 1) * BH * 2;

  prep_convert<<<dim3((4 * HDIM * HDIM + 255) / 256), dim3(256), 0, stream>>>(
      Whh_f, Wout_f, h0, Whh, Wout, hts);
  prep_ptable<<<dim3((VOCAB * 4096) / 256), dim3(256), 0, stream>>>(
      emb, Wih, bih, bhh, Pb);

  for (int t = 0; t < T_STEPS; ++t) {
    __hip_bfloat16* hp = hts + (full ? (size_t)t * BH : (size_t)(t & 1) * BH);
    __hip_bfloat16* hn =
        hts + (full ? (size_t)(t + 1) * BH : (size_t)((t + 1) & 1) * BH);
    const float* cin = (t == 0) ? c0 : cT;
    if (t == T_STEPS - 1) {
      lstm_step_kernel<true><<<dim3(512), dim3(512), 0, stream>>>(
          ids + (size_t)t * BSZ, hp, Whh, Pb, cin, cT, hn, hT);
    } else {
      lstm_step_kernel<false><<<dim3(512), dim3(512), 0, stream>>>(
          ids + (size_t)t * BSZ, hp, Whh, Pb, cin, cT, hn, nullptr);
    }
    if (!full) {
      scores_kernel<<<dim3(BSZ / 128), dim3(256), 0, stream>>>(
          hn, Wout, bout, scores + (size_t)t * BSZ * VOCAB);
    }
  }
  if (full) {
    scores_kernel<<<dim3(T_STEPS * BSZ / 128), dim3(256), 0, stream>>>(
        hts + BH, Wout, bout, scores);
  }
}

// Round 8
// 1094.124 us; speedup vs baseline: 1.0692x; 1.0692x over previous
//
#include <hip/hip_runtime.h>
#include <hip/hip_bf16.h>

// CharDecoder: T=21, B=4096, H=1024, E=50, V=96
// d_out: scores(T,B,V) fp32 | h_T(B,H) | c_T(B,H)

#define T_STEPS 21
#define BSZ 4096
#define HDIM 1024
#define VOCAB 96
#define EDIM 50

typedef __attribute__((ext_vector_type(8))) short short8;
typedef __attribute__((ext_vector_type(4))) short shortx4;
typedef __attribute__((ext_vector_type(4))) float f32x4;

#define GLL16(g, l)                                                        \
  __builtin_amdgcn_global_load_lds(                                        \
      (const __attribute__((address_space(1))) void*)(g),                  \
      (__attribute__((address_space(3))) void*)(l), 16, 0, 0)

#define ASM_BARRIER() asm volatile("s_barrier" ::: "memory")
#define ASM_VMCNT4() asm volatile("s_waitcnt vmcnt(4)" ::: "memory")
#define ASM_VMCNT0() asm volatile("s_waitcnt vmcnt(0)" ::: "memory")

__device__ __forceinline__ float sigmoidf_fast(float x) {
  return 1.0f / (1.0f + __expf(-x));
}
__device__ __forceinline__ float tanhf_fast(float x) {
  return 2.0f / (1.0f + __expf(-2.0f * x)) - 1.0f;
}
__device__ __forceinline__ float b2f(short s) {
  return __uint_as_float(((unsigned int)(unsigned short)s) << 16);
}

// ---- prep: fp32 -> bf16 weight/state conversion -------------------------
__global__ void prep_convert(const float* __restrict__ Whh_f,
                             const float* __restrict__ Wout_f,
                             const float* __restrict__ h0,
                             __hip_bfloat16* __restrict__ Whh,
                             __hip_bfloat16* __restrict__ Wout,
                             __hip_bfloat16* __restrict__ hb0) {
  int idx = blockIdx.x * 256 + threadIdx.x;
  if (idx < 4 * HDIM * HDIM) {
    Whh[idx] = __float2bfloat16(Whh_f[idx]);
    hb0[idx] = __float2bfloat16(h0[idx]);
  }
  if (idx < VOCAB * HDIM) Wout[idx] = __float2bfloat16(Wout_f[idx]);
}

// ---- prep: Pb[j>>6][v][unit 64][gate 4] (bf16) = emb.W_ih + b_ih + b_hh -
__global__ void prep_ptable(const float* __restrict__ emb,
                            const float* __restrict__ Wih,
                            const float* __restrict__ bih,
                            const float* __restrict__ bhh,
                            __hip_bfloat16* __restrict__ Pb) {
  int idx = blockIdx.x * 256 + threadIdx.x;  // 96*4096
  int v = idx >> 12, g = idx & 4095;         // g = gate*1024 + j
  int gate = g >> 10, j = g & 1023;
  const float* er = emb + v * EDIM;
  const float* wr = Wih + g * EDIM;
  float s = bih[g] + bhh[g];
#pragma unroll 10
  for (int e = 0; e < EDIM; ++e) s += er[e] * wr[e];
  Pb[(size_t)(j >> 6) * 24576 + v * 256 + (j & 63) * 4 + gate] =
      __float2bfloat16(s);
}

// ---- 256x256 LSTM step, BK=32, TRIPLE-buffered, depth-2 pipeline --------
// Tile: 256 batch rows x (4 gates x 64 units); grid 256 (1 block/CU);
// 8 waves (2M x 4N), wave tile 128x64; LDS 3 bufs x 32KB (A 16K + B 16K).
// Depth-2 attack on the 2-phase plateau (R6/R7 ruled out LDS volume,
// barrier count, occupancy): stage tile k+2 while computing k (2 full
// tile-times of latency cover) and ONE barrier per tile.
// Per tile k: [barrier; 12 ds_read_b128; 4 GLL16 stage(k+2)->buf((k+2)%3);
//             setprio(1); 32 MFMA; setprio(0); vmcnt(4)].
// WAR proof for 1-barrier/tile: stage(k+2) targets phys buf (k-1)%3; all
// waves' reads of it (tile k-1) retired before their MFMA_{k-1} (lgkmcnt),
// which precedes barrier_k; stage issues after barrier_k -> safe.
// vmcnt proof: at tile-k end, outstanding = tile k+1's 4 (issued at k-1)
// + tile k+2's 4 (just issued); vmcnt(4) drains k+1's -> tile k+1 proven,
// k+2 stays fully in flight. k==30: vmcnt(0); k==31: none.
// LDS layout (per buffer): row-pairs packed. line = row>>1 (128B/line);
// slot S = ((row&1)<<2)|kchunk (4 x 8-elem chunks of BK=32), stored at
// slot' = S ^ (line&7). A lines [0,128) byte 0; B lines [0,128) byte 16384.

#define TILE(kk, CB, SB, DOSTAGE, VMW)                                     \
  {                                                                        \
    ASM_BARRIER();                                                         \
    const __hip_bfloat16* bufE =                                           \
        (const __hip_bfloat16*)(smem + (CB) * 32768);                      \
    short8 af[8], bf[4];                                                   \
    _Pragma("unroll") for (int mi = 0; mi < 8; ++mi)                       \
        af[mi] = *(const short8*)&bufE[a_off[mi]];                         \
    _Pragma("unroll") for (int g = 0; g < 4; ++g)                          \
        bf[g] = *(const short8*)&bufE[b_off[g]];                           \
    if (DOSTAGE) {                                                         \
      GLL16(hprev + aSrc[0] + ((kk) + 2) * 32,                             \
            smem + (SB) * 32768 + aDst0);                                  \
      GLL16(hprev + aSrc[1] + ((kk) + 2) * 32,                             \
            smem + (SB) * 32768 + aDst1);                                  \
      GLL16(Whh + bSrc[0] + ((kk) + 2) * 32,                               \
            smem + (SB) * 32768 + bDst0);                                  \
      GLL16(Whh + bSrc[1] + ((kk) + 2) * 32,                               \
            smem + (SB) * 32768 + bDst1);                                  \
    }                                                                      \
    __builtin_amdgcn_s_setprio(1);                                         \
    _Pragma("unroll") for (int mi = 0; mi < 8; ++mi)                       \
        _Pragma("unroll") for (int g = 0; g < 4; ++g)                      \
            acc[mi][g] = __builtin_amdgcn_mfma_f32_16x16x32_bf16(          \
                af[mi], bf[g], acc[mi][g], 0, 0, 0);                       \
    __builtin_amdgcn_s_setprio(0);                                         \
    VMW;                                                                   \
  }

template <bool LAST>
__global__ __launch_bounds__(512, 2) void lstm_step_kernel(
    const int* __restrict__ ids,               // B ints (this t)
    const __hip_bfloat16* __restrict__ hprev,  // B x H
    const __hip_bfloat16* __restrict__ Whh,    // 4H x H (torch order i,f,g,o)
    const __hip_bfloat16* __restrict__ Pb,     // 16 x 96 x 64 x 4 (bf16)
    const float* __restrict__ c_in,            // B x H
    float* __restrict__ c_out,                 // B x H
    __hip_bfloat16* __restrict__ hnext,        // B x H
    float* __restrict__ hf32)                  // B x H (LAST only)
{
  __shared__ __align__(16) char smem[98304];  // 3 x 32KB

  const int tid = threadIdx.x;
  const int wid = tid >> 6;
  const int lane = tid & 63;
  const int wr = wid >> 2;  // 0..1 (M half: 128 rows)
  const int wc = wid & 3;   // 0..3 (N quarter: 16 units x 4 gates)
  const int u16 = lane & 15;
  const int k16q = lane >> 4;

  // XCD swizzle: the 16 jt-blocks sharing an A panel (same mt) on one XCD.
  const int bid = blockIdx.x;
  const int mt = (bid & 7) * 2 + ((bid >> 3) & 1);  // 0..15
  const int jt = bid >> 4;                          // 0..15 (64-unit block)
  const int m0 = mt * 256;

  // ---- fragment read offsets (elements), swizzled row-pair layout ----
  int a_off[8], b_off[4];
  {
    const int S = ((u16 & 1) << 2) | k16q;
#pragma unroll
    for (int mi = 0; mi < 8; ++mi) {
      const int La = wr * 64 + mi * 8 + (u16 >> 1);  // rows wr*128+mi*16+u16
      a_off[mi] = La * 64 + (S ^ (La & 7)) * 8;
    }
#pragma unroll
    for (int g = 0; g < 4; ++g) {
      const int Lb = wc * 32 + g * 8 + (u16 >> 1);  // B row wc*64+g*16+u16
      b_off[g] = 8192 + Lb * 64 + (S ^ (Lb & 7)) * 8;
    }
  }

  // ---- staging bases (pre-swizzled global src, linear LDS dest) ----
  size_t aSrc[2], bSrc[2];
  const int aDst0 = wid * 2048;
  const int aDst1 = wid * 2048 + 1024;
  const int bDst0 = 16384 + wid * 2048;
  const int bDst1 = 16384 + wid * 2048 + 1024;
  {
    const int lrow = lane >> 3;
    const int Sp = lane & 7;  // slot' this lane writes
#pragma unroll
    for (int q = 0; q < 2; ++q) {
      const int La = wid * 16 + q * 8 + lrow;
      const int S = Sp ^ (La & 7);
      const int arow = 2 * La + (S >> 2);
      aSrc[q] = (size_t)(m0 + arow) * HDIM + (S & 3) * 8;
      const int Lb = wid * 16 + q * 8 + lrow;
      const int S2 = Sp ^ (Lb & 7);
      const int n = 2 * Lb + (S2 >> 2);  // B row index 0..255
      const int q4 = n >> 6, gate = (n >> 4) & 3, u = n & 15;
      bSrc[q] = (size_t)(gate * HDIM + jt * 64 + q4 * 16 + u) * HDIM +
                (S2 & 3) * 8;
    }
  }

  // prologue: tile0 -> buf0, tile1 -> buf1 (8 GLL16), then counted wait
  GLL16(hprev + aSrc[0], smem + aDst0);
  GLL16(hprev + aSrc[1], smem + aDst1);
  GLL16(Whh + bSrc[0], smem + bDst0);
  GLL16(Whh + bSrc[1], smem + bDst1);
  GLL16(hprev + aSrc[0] + 32, smem + 32768 + aDst0);
  GLL16(hprev + aSrc[1] + 32, smem + 32768 + aDst1);
  GLL16(Whh + bSrc[0] + 32, smem + 32768 + bDst0);
  GLL16(Whh + bSrc[1] + 32, smem + 32768 + bDst1);
  ASM_VMCNT4();  // tile0 landed; tile1's 4 stay in flight

  f32x4 acc[8][4] = {};  // [M-frag][gate]

#pragma unroll 1
  for (int kb = 0; kb < 30; kb += 3) {
    TILE(kb, 0, 2, true, ASM_VMCNT4());
    TILE(kb + 1, 1, 0, true, ASM_VMCNT4());
    TILE(kb + 2, 2, 1, true, ASM_VMCNT4());
  }
  TILE(30, 0, 0, false, ASM_VMCNT0());
  TILE(31, 1, 0, false, {});
  ASM_BARRIER();  // all waves done with tile31 reads before Pb overwrite

  // c_in prefetch (overlaps Pb staging); disjoint (row,jcol) tiles.
  const int jcol = jt * 64 + wc * 16 + u16;  // output unit j
  float cpre[8][4];
#pragma unroll
  for (int mi = 0; mi < 8; ++mi)
#pragma unroll
    for (int r = 0; r < 4; ++r)
      cpre[mi][r] = c_in[(size_t)(m0 + wr * 128 + mi * 16 + k16q * 4 + r) *
                             HDIM +
                         jcol];

  // stage bf16 P slice (48 KB) into now-dead LDS.
  {
    const __hip_bfloat16* Pbj = Pb + (size_t)jt * 24576;
#pragma unroll
    for (int i = 0; i < 6; ++i)
      GLL16(Pbj + (wid * 6 + i) * 512 + lane * 8,
            smem + (wid * 6 + i) * 1024);
  }
  ASM_VMCNT0();
  ASM_BARRIER();

  // epilogue: 4 gates of unit jcol contiguous -> one b64 gather per output
  const __hip_bfloat16* sPb = (const __hip_bfloat16*)smem;
  const int uo4 = (wc * 16 + u16) * 4;
  const int rb = m0 + wr * 128 + k16q * 4;
#pragma unroll
  for (int mi = 0; mi < 8; ++mi) {
#pragma unroll
    for (int r = 0; r < 4; ++r) {
      const int row = rb + mi * 16 + r;
      const int id = ids[row];
      const shortx4 pv = *(const shortx4*)&sPb[id * 256 + uo4];
      float iv = acc[mi][0][r] + b2f(pv[0]);
      float fv = acc[mi][1][r] + b2f(pv[1]);
      float gv = acc[mi][2][r] + b2f(pv[2]);
      float ov = acc[mi][3][r] + b2f(pv[3]);
      iv = sigmoidf_fast(iv);
      fv = sigmoidf_fast(fv);
      gv = tanhf_fast(gv);
      ov = sigmoidf_fast(ov);
      const size_t off = (size_t)row * HDIM + jcol;
      const float cc = fv * cpre[mi][r] + iv * gv;
      c_out[off] = cc;
      const float hh = ov * tanhf_fast(cc);
      hnext[off] = __float2bfloat16(hh);
      if (LAST) hf32[off] = hh;
    }
  }
}

// ---- scores: LDS-tiled GEMM, 128 rows x 96 cols per block, BK=128 -------
__global__ __launch_bounds__(256, 2) void scores_kernel(
    const __hip_bfloat16* __restrict__ h,     // rows x H (bf16)
    const __hip_bfloat16* __restrict__ Wout,  // 96 x H
    const float* __restrict__ bout,           // 96
    float* __restrict__ out)                  // rows x 96
{
  __shared__ __align__(16) __hip_bfloat16 sA[128 * 128];  // 32 KB
  __shared__ __align__(16) __hip_bfloat16 sB[96 * 128];   // 24 KB

  const int tid = threadIdx.x;
  const int wave = tid >> 6, lane = tid & 63;
  const int u16 = lane & 15, k16q = lane >> 4;
  const long r0 = (long)blockIdx.x * 128;

  f32x4 acc[2][6] = {};  // wave: 32 rows x 96 cols

  const int srow4 = lane >> 4;
  const int sslot = lane & 15;

  for (int k0 = 0; k0 < HDIM; k0 += 128) {
#pragma unroll
    for (int i = 0; i < 8; ++i) {  // A: 32 rows/wave
      int row = wave * 32 + i * 4 + srow4;
      int gg = sslot ^ (row & 15);
      GLL16(h + (r0 + row) * HDIM + k0 + gg * 8,
            &sA[(wave * 32 + i * 4) * 128]);
    }
#pragma unroll
    for (int i = 0; i < 6; ++i) {  // B: 24 rows/wave
      int row = wave * 24 + i * 4 + srow4;
      int gg = sslot ^ (row & 15);
      GLL16(Wout + (size_t)row * HDIM + k0 + gg * 8,
            &sB[(wave * 24 + i * 4) * 128]);
    }
    __syncthreads();
#pragma unroll
    for (int kk = 0; kk < 128; kk += 32) {
      const int sl = (((kk >> 3) + k16q) ^ u16) * 8;
      short8 af[2], bf[6];
#pragma unroll
      for (int mi = 0; mi < 2; ++mi)
        af[mi] = *(const short8*)&sA[(wave * 32 + mi * 16 + u16) * 128 + sl];
#pragma unroll
      for (int ni = 0; ni < 6; ++ni)
        bf[ni] = *(const short8*)&sB[(ni * 16 + u16) * 128 + sl];
#pragma unroll
      for (int mi = 0; mi < 2; ++mi)
#pragma unroll
        for (int ni = 0; ni < 6; ++ni)
          acc[mi][ni] = __builtin_amdgcn_mfma_f32_16x16x32_bf16(
              af[mi], bf[ni], acc[mi][ni], 0, 0, 0);
    }
    __syncthreads();
  }

#pragma unroll
  for (int ni = 0; ni < 6; ++ni) {
    int v = ni * 16 + u16;
    float bv = bout[v];
#pragma unroll
    for (int mi = 0; mi < 2; ++mi)
#pragma unroll
      for (int r = 0; r < 4; ++r) {
        long grow = r0 + wave * 32 + mi * 16 + k16q * 4 + r;
        out[grow * VOCAB + v] = acc[mi][ni][r] + bv;
      }
  }
}

extern "C" void kernel_launch(void* const* d_in, const int* in_sizes, int n_in,
                              void* d_out, int out_size, void* d_ws,
                              size_t ws_size, hipStream_t stream) {
  const int* ids = (const int*)d_in[0];
  const float* h0 = (const float*)d_in[1];
  const float* c0 = (const float*)d_in[2];
  const float* emb = (const float*)d_in[3];
  const float* Wih = (const float*)d_in[4];
  const float* Whh_f = (const float*)d_in[5];
  const float* bih = (const float*)d_in[6];
  const float* bhh = (const float*)d_in[7];
  const float* Wout_f = (const float*)d_in[8];
  const float* bout = (const float*)d_in[9];

  float* out = (float*)d_out;
  float* scores = out;                              // T*B*V
  float* hT = out + (size_t)T_STEPS * BSZ * VOCAB;  // B*H
  float* cT = hT + (size_t)BSZ * HDIM;              // B*H

  const size_t BH = (size_t)BSZ * HDIM;
  char* w = (char*)d_ws;
  __hip_bfloat16* Pb = (__hip_bfloat16*)w;   w += (size_t)16 * 24576 * 2;
  __hip_bfloat16* Whh = (__hip_bfloat16*)w;  w += (size_t)4 * HDIM * HDIM * 2;
  __hip_bfloat16* Wout = (__hip_bfloat16*)w; w += (size_t)VOCAB * HDIM * 2;
  __hip_bfloat16* hts = (__hip_bfloat16*)w;  // 22*BH (full) or 2*BH (pingpong)
  size_t base = (size_t)16 * 24576 * 2 + (size_t)4 * HDIM * HDIM * 2 +
                (size_t)VOCAB * HDIM * 2;
  const bool full = ws_size >= base + (size_t)(T_STEPS + 1) * BH * 2;

  prep_convert<<<dim3((4 * HDIM * HDIM + 255) / 256), dim3(256), 0, stream>>>(
      Whh_f, Wout_f, h0, Whh, Wout, hts);
  prep_ptable<<<dim3((VOCAB * 4096) / 256), dim3(256), 0, stream>>>(
      emb, Wih, bih, bhh, Pb);

  for (int t = 0; t < T_STEPS; ++t) {
    __hip_bfloat16* hp = hts + (full ? (size_t)t * BH : (size_t)(t & 1) * BH);
    __hip_bfloat16* hn =
        hts + (full ? (size_t)(t + 1) * BH : (size_t)((t + 1) & 1) * BH);
    const float* cin = (t == 0) ? c0 : cT;
    if (t == T_STEPS - 1) {
      lstm_step_kernel<true><<<dim3(256), dim3(512), 0, stream>>>(
          ids + (size_t)t * BSZ, hp, Whh, Pb, cin, cT, hn, hT);
    } else {
      lstm_step_kernel<false><<<dim3(256), dim3(512), 0, stream>>>(
          ids + (size_t)t * BSZ, hp, Whh, Pb, cin, cT, hn, nullptr);
    }
    if (!full) {
      scores_kernel<<<dim3(BSZ / 128), dim3(256), 0, stream>>>(
          hn, Wout, bout, scores + (size_t)t * BSZ * VOCAB);
    }
  }
  if (full) {
    scores_kernel<<<dim3(T_STEPS * BSZ / 128), dim3(256), 0, stream>>>(
        hts + BH, Wout, bout, scores);
  }
}